// Round 10
// baseline (288.973 us; speedup 1.0000x reference)
//
#include <hip/hip_runtime.h>
#include <hip/hip_bf16.h>
#include <math.h>

#define BB 16
#define SS 2048
#define DD 512
#define NDOCS 200000
#define TOPK 5
#define EPSN 1e-12f
#define NEG_INF (-3.0e38f)

#define NB3 391                 // K3 blocks (512 thr = 8 waves each)
#define NW3 (NB3 * 8)           // 3128 scanning waves
#define NT3 (NDOCS / 16)        // 12500 16-doc tiles (exact)
#define QSTR 520                // padded q row stride (shorts)

typedef short s16x8 __attribute__((ext_vector_type(8)));
typedef float f32x4 __attribute__((ext_vector_type(4)));

__device__ __forceinline__ short f2bf(float f) {
    __bf16 b = (__bf16)f;
    short s;
    __builtin_memcpy(&s, &b, 2);
    return s;
}

// ---------------- K1: partial mean pool: partial[32][16][512] ----------------
__global__ __launch_bounds__(128) void k1_mean_partial(
    const float* __restrict__ hs, float* __restrict__ partial) {
    int b = blockIdx.y, sc = blockIdx.x;
    int t = threadIdx.x;
    const float4* src = (const float4*)(hs + (size_t)(b * SS + sc * 64) * DD);
    float4 acc = {0.f, 0.f, 0.f, 0.f};
    for (int s = 0; s < 64; ++s) {
        float4 v = src[(size_t)s * 128 + t];
        acc.x += v.x; acc.y += v.y; acc.z += v.z; acc.w += v.w;
    }
    ((float4*)partial)[(size_t)(sc * BB + b) * 128 + t] = acc;
}

// ---------------- K2: fused mean-reduce + Wq GEMV + l2norm ----------------
// grid 16 (batch), 512 threads (one output row per thread)
__global__ __launch_bounds__(512) void k2_query(
    const float* __restrict__ partial, const float* __restrict__ Wq,
    const float* __restrict__ bqv, float* __restrict__ qv) {
    int b = blockIdx.x, t = threadIdx.x;
    __shared__ float meanv[DD];
    __shared__ float red[8];
    float s = 0.f;
    for (int c = 0; c < 32; ++c) s += partial[(size_t)(c * BB + b) * DD + t];
    meanv[t] = s * (1.0f / 2048.0f);
    __syncthreads();
    const float4* wr = (const float4*)(Wq + (size_t)t * DD);
    const float4* mv = (const float4*)meanv;
    float acc = bqv[t];
#pragma unroll 8
    for (int k4 = 0; k4 < DD / 4; ++k4) {
        float4 w = wr[k4], m = mv[k4];
        acc = fmaf(w.x, m.x, acc); acc = fmaf(w.y, m.y, acc);
        acc = fmaf(w.z, m.z, acc); acc = fmaf(w.w, m.w, acc);
    }
    float ss = acc * acc;
#pragma unroll
    for (int m = 1; m < 64; m <<= 1) ss += __shfl_xor(ss, m);
    if ((t & 63) == 0) red[t >> 6] = ss;
    __syncthreads();
    float tot = 0.f;
#pragma unroll
    for (int i = 0; i < 8; ++i) tot += red[i];
    float inv = 1.0f / fmaxf(sqrtf(tot), EPSN);
    qv[(size_t)b * DD + t] = acc * inv;
}

// ---------------- K3: barrier-free streaming MFMA scan, depth-4 ----------------
// 391 blocks x 512 thr (8 waves). Wave owns 16-doc tiles (grid-stride).
// Lane: bq=lane&15 -> doc row (A) / batch col (B); kg=lane>>4 -> k-slice.
// Depth-4 chunk prefetch (pa/pb[c&3], static after unroll): ~8 loads in flight.
// q in LDS bf16 hi/lo planes (stride 520). R3/R9-verified 3-MFMA numerics.
__global__ __launch_bounds__(512) void k3_scores(
    const float* __restrict__ docs, const float* __restrict__ qv,
    float* __restrict__ cand_s, int* __restrict__ cand_i) {
    __shared__ short qS[2][BB * QSTR];   // 33.3KB

    int t = threadIdx.x;
    int w = t >> 6, lane = t & 63;
    int bq = lane & 15, kg = lane >> 4;

    for (int u = t; u < BB * DD; u += 512) {
        int b = u >> 9, k = u & 511;
        float f = qv[u];
        unsigned uu = __float_as_uint(f);
        qS[0][b * QSTR + k] = (short)(uu >> 16);
        qS[1][b * QSTR + k] = f2bf(f - __uint_as_float(uu & 0xFFFF0000u));
    }
    __syncthreads();

    int gw = blockIdx.x * 8 + w;

    float lv[TOPK]; int li[TOPK];
#pragma unroll
    for (int r = 0; r < TOPK; ++r) { lv[r] = NEG_INF; li[r] = 0x7fffffff; }

    auto ins = [&](float s, int di) {
        if (s > lv[4] || (s == lv[4] && di < li[4])) {
            lv[4] = s; li[4] = di;
#pragma unroll
            for (int k = 4; k > 0; --k) {
                if (lv[k] > lv[k - 1] || (lv[k] == lv[k - 1] && li[k] < li[k - 1])) {
                    float tv = lv[k]; lv[k] = lv[k - 1]; lv[k - 1] = tv;
                    int   ti = li[k]; li[k] = li[k - 1]; li[k - 1] = ti;
                }
            }
        }
    };

    const short* qh_base = &qS[0][bq * QSTR + kg * 8];
    const short* ql_base = &qS[1][bq * QSTR + kg * 8];

    long tt = gw;
    const float* dpt = docs + ((long)tt * 16 + bq) * DD + kg * 8;

    f32x4 pa[4], pb[4];
#pragma unroll
    for (int i = 0; i < 4; ++i) {
        pa[i] = *(const f32x4*)(dpt + i * 32);
        pb[i] = *(const f32x4*)(dpt + i * 32 + 4);
    }

    while (tt < NT3) {
        long tt2 = (tt + NW3 < NT3) ? tt + NW3 : tt;
        const float* dpn = docs + (tt2 * 16 + bq) * DD + kg * 8;

        f32x4 acc1 = {0.f, 0.f, 0.f, 0.f};
        f32x4 acc2 = {0.f, 0.f, 0.f, 0.f};
        float nrm = 0.f;

#pragma unroll
        for (int c = 0; c < 16; ++c) {
            const int sl = c & 3;                  // static after unroll
            float ef[8] = {pa[sl][0], pa[sl][1], pa[sl][2], pa[sl][3],
                           pb[sl][0], pb[sl][1], pb[sl][2], pb[sl][3]};
            s16x8 ah, al;
#pragma unroll
            for (int i = 0; i < 8; ++i) {
                unsigned u = __float_as_uint(ef[i]);
                ah[i] = (short)(u >> 16);
                al[i] = f2bf(ef[i] - __uint_as_float(u & 0xFFFF0000u));
                nrm = fmaf(ef[i], ef[i], nrm);
            }
            s16x8 qh = *(const s16x8*)(qh_base + c * 32);
            s16x8 ql = *(const s16x8*)(ql_base + c * 32);
            acc1 = __builtin_amdgcn_mfma_f32_16x16x32_bf16(ah, qh, acc1, 0, 0, 0);
            acc2 = __builtin_amdgcn_mfma_f32_16x16x32_bf16(ah, ql, acc2, 0, 0, 0);
            acc2 = __builtin_amdgcn_mfma_f32_16x16x32_bf16(al, qh, acc2, 0, 0, 0);
            // refill slot with chunk c+4 (this tile or next tile's chunk c-12)
            if (c < 12) {
                pa[sl] = *(const f32x4*)(dpt + (c + 4) * 32);
                pb[sl] = *(const f32x4*)(dpt + (c + 4) * 32 + 4);
            } else {
                pa[sl] = *(const f32x4*)(dpn + (c - 12) * 32);
                pb[sl] = *(const f32x4*)(dpn + (c - 12) * 32 + 4);
            }
        }

        float nn = nrm + __shfl_xor(nrm, 16);
        nn += __shfl_xor(nn, 32);
        float invn = 1.0f / fmaxf(sqrtf(nn), EPSN);
        f32x4 acct = acc1 + acc2;
#pragma unroll
        for (int r = 0; r < 4; ++r) {
            float iv = __shfl(invn, kg * 4 + r);
            ins(acct[r] * iv, (int)(tt * 16 + kg * 4 + r));
        }

        tt += NW3;
        dpt = dpn;
    }

#pragma unroll
    for (int step = 16; step <= 32; step <<= 1) {
        float ov[TOPK]; int oi[TOPK];
#pragma unroll
        for (int r = 0; r < TOPK; ++r) {
            ov[r] = __shfl_xor(lv[r], step);
            oi[r] = __shfl_xor(li[r], step);
        }
#pragma unroll
        for (int r = 0; r < TOPK; ++r) ins(ov[r], oi[r]);
    }

    if (kg == 0) {
#pragma unroll
        for (int r = 0; r < TOPK; ++r) {
            cand_s[((long)gw * BB + bq) * TOPK + r] = lv[r];
            cand_i[((long)gw * BB + bq) * TOPK + r] = li[r];
        }
    }
}

// ---------------- K4: merge top-5, softmax, context, ctx-logit, outputs ------
__global__ __launch_bounds__(256) void k4_finalize(
    const float* __restrict__ docs, const float* __restrict__ Wg,
    const float* __restrict__ bgt, const float* __restrict__ cand_s,
    const int* __restrict__ cand_i, float* __restrict__ ctx,
    float* __restrict__ ctxb, float* __restrict__ outp) {
    int b = blockIdx.x, t = threadIdx.x;
    __shared__ float sv[256];
    __shared__ int   si[256];
    __shared__ float topv[TOPK];
    __shared__ int   topi[TOPK];
    __shared__ float red[4];
    __shared__ float nrm5[TOPK];
    __shared__ float wts[TOPK];
    __shared__ float ctxLds[DD];

    float lv[TOPK]; int li[TOPK];
#pragma unroll
    for (int r = 0; r < TOPK; ++r) { lv[r] = NEG_INF; li[r] = 0x7fffffff; }

    for (int j = t; j < NW3 * TOPK; j += 256) {
        int blk = j / TOPK, r = j - blk * TOPK;
        float s = cand_s[(long)blk * (BB * TOPK) + b * TOPK + r];
        int  di = cand_i[(long)blk * (BB * TOPK) + b * TOPK + r];
        if (s > lv[TOPK - 1] || (s == lv[TOPK - 1] && di < li[TOPK - 1])) {
            lv[TOPK - 1] = s; li[TOPK - 1] = di;
#pragma unroll
            for (int k = TOPK - 1; k > 0; --k) {
                if (lv[k] > lv[k - 1] || (lv[k] == lv[k - 1] && li[k] < li[k - 1])) {
                    float tv = lv[k]; lv[k] = lv[k - 1]; lv[k - 1] = tv;
                    int   ti = li[k]; li[k] = li[k - 1]; li[k - 1] = ti;
                }
            }
        }
    }

    int p = 0;
    for (int r = 0; r < TOPK; ++r) {
        float hv = (p < TOPK) ? lv[p] : NEG_INF;
        int   hi = (p < TOPK) ? li[p] : 0x7fffffff;
        sv[t] = hv; si[t] = hi;
        __syncthreads();
        for (int off = 128; off > 0; off >>= 1) {
            if (t < off) {
                float ov = sv[t + off]; int oi = si[t + off];
                if (ov > sv[t] || (ov == sv[t] && oi < si[t])) { sv[t] = ov; si[t] = oi; }
            }
            __syncthreads();
        }
        if (t == 0) { topv[r] = sv[0]; topi[r] = si[0]; }
        __syncthreads();
        if (hv == topv[r] && hi == topi[r]) ++p;
        __syncthreads();
    }

    for (int r = 0; r < TOPK; ++r) {
        const float* dr = docs + (size_t)topi[r] * DD;
        float s2 = dr[t] * dr[t] + dr[t + 256] * dr[t + 256];
#pragma unroll
        for (int m = 1; m < 64; m <<= 1) s2 += __shfl_xor(s2, m);
        if ((t & 63) == 0) red[t >> 6] = s2;
        __syncthreads();
        if (t == 0) nrm5[r] = sqrtf(red[0] + red[1] + red[2] + red[3]);
        __syncthreads();
    }

    if (t == 0) {
        float m = topv[0];
        float e[TOPK], s = 0.f;
#pragma unroll
        for (int r = 0; r < TOPK; ++r) { e[r] = expf(topv[r] - m); s += e[r]; }
#pragma unroll
        for (int r = 0; r < TOPK; ++r) wts[r] = e[r] / s;
    }
    __syncthreads();

    for (int j = t; j < DD; j += 256) {
        float c = 0.f;
#pragma unroll
        for (int r = 0; r < TOPK; ++r)
            c += wts[r] * docs[(size_t)topi[r] * DD + j] / fmaxf(nrm5[r], EPSN);
        ctxLds[j] = c;
        ctx[(size_t)b * DD + j] = c;
    }
    __syncthreads();

    // fused ctx-logit GEMV: rows t and t+256
    const float4* cv = (const float4*)ctxLds;
#pragma unroll
    for (int rr = 0; rr < 2; ++rr) {
        int row = t + rr * 256;
        const float4* wr = (const float4*)(Wg + (size_t)row * (2 * DD) + DD);
        float acc = bgt[row];
#pragma unroll 8
        for (int k4 = 0; k4 < DD / 4; ++k4) {
            float4 wv = wr[k4], mv = cv[k4];
            acc = fmaf(wv.x, mv.x, acc); acc = fmaf(wv.y, mv.y, acc);
            acc = fmaf(wv.z, mv.z, acc); acc = fmaf(wv.w, mv.w, acc);
        }
        ctxb[(size_t)b * DD + row] = acc;
    }

    if (t < TOPK) {
        outp[b * TOPK + t] = topv[t];
        outp[BB * TOPK + b * TOPK + t] = (float)topi[t];
    }
}

// ---------------- K5: bf16 MFMA gate GEMM + fused epilogue ----------------
#define BK 32
__global__ __launch_bounds__(512, 2) void k5_gemm_fused(
    const float* __restrict__ hs, const float* __restrict__ Wg,
    const float* __restrict__ ctx, const float* __restrict__ ctxb,
    float* __restrict__ outF) {
    __shared__ short At[128][BK];
    __shared__ short Bt[512][BK];
    __shared__ float ctxLds[DD];
    __shared__ float ctxbLds[DD];

    int bm = blockIdx.x;
    int t = threadIdx.x;
    int wv = t >> 6, lane = t & 63, ln = lane & 15, kg = lane >> 4;
    int wm = (wv >> 2) * 64, wn = (wv & 3) * 128;
    int bbatch = bm >> 4;

    ctxLds[t]  = ctx[(size_t)bbatch * DD + t];
    ctxbLds[t] = ctxb[(size_t)bbatch * DD + t];

    float4 pf[5][2];
    auto gload = [&](int kt) {
        {
            const float* src = hs + (size_t)(bm * 128 + (t >> 2)) * DD + kt * BK + (t & 3) * 8;
            pf[0][0] = ((const float4*)src)[0];
            pf[0][1] = ((const float4*)src)[1];
        }
#pragma unroll
        for (int i = 0; i < 4; ++i) {
            int u = t + i * 512;
            const float* src = Wg + (size_t)(u >> 2) * (2 * DD) + kt * BK + (u & 3) * 8;
            pf[1 + i][0] = ((const float4*)src)[0];
            pf[1 + i][1] = ((const float4*)src)[1];
        }
    };
    auto cvt1 = [&](float4 lo, float4 hi) {
        s16x8 cv;
        cv[0] = f2bf(lo.x); cv[1] = f2bf(lo.y); cv[2] = f2bf(lo.z); cv[3] = f2bf(lo.w);
        cv[4] = f2bf(hi.x); cv[5] = f2bf(hi.y); cv[6] = f2bf(hi.z); cv[7] = f2bf(hi.w);
        return cv;
    };
    auto cvtwrite = [&]() {
        {
            int row = t >> 2, slot = t & 3;
            int sl = slot ^ ((row >> 1) & 3);
            *(s16x8*)(&At[row][sl * 8]) = cvt1(pf[0][0], pf[0][1]);
        }
#pragma unroll
        for (int i = 0; i < 4; ++i) {
            int u = t + i * 512;
            int row = u >> 2, slot = u & 3;
            int sl = slot ^ ((row >> 1) & 3);
            *(s16x8*)(&Bt[row][sl * 8]) = cvt1(pf[1 + i][0], pf[1 + i][1]);
        }
    };

    f32x4 accv[4][8];
#pragma unroll
    for (int i = 0; i < 4; ++i)
#pragma unroll
        for (int j = 0; j < 8; ++j) accv[i][j] = (f32x4){0.f, 0.f, 0.f, 0.f};

    gload(0);
    for (int kt = 0; kt < DD / BK; ++kt) {
        __syncthreads();
        cvtwrite();
        if (kt + 1 < DD / BK) gload(kt + 1);
        __syncthreads();
        s16x8 af[4], bfr[8];
#pragma unroll
        for (int mi = 0; mi < 4; ++mi) {
            int row = wm + mi * 16 + ln;
            int sl = kg ^ ((row >> 1) & 3);
            af[mi] = *(const s16x8*)&At[row][sl * 8];
        }
#pragma unroll
        for (int nj = 0; nj < 8; ++nj) {
            int row = wn + nj * 16 + ln;
            int sl = kg ^ ((row >> 1) & 3);
            bfr[nj] = *(const s16x8*)&Bt[row][sl * 8];
        }
#pragma unroll
        for (int mi = 0; mi < 4; ++mi)
#pragma unroll
            for (int nj = 0; nj < 8; ++nj)
                accv[mi][nj] = __builtin_amdgcn_mfma_f32_16x16x32_bf16(
                    af[mi], bfr[nj], accv[mi][nj], 0, 0, 0);
    }

#pragma unroll
    for (int mi = 0; mi < 4; ++mi)
#pragma unroll
        for (int nj = 0; nj < 8; ++nj)
#pragma unroll
            for (int r = 0; r < 4; ++r) {
                int ri = wm + mi * 16 + kg * 4 + r;
                int ci = wn + nj * 16 + ln;
                size_t grow = (size_t)bm * 128 + ri;
                float logit = accv[mi][nj][r] + ctxbLds[ci];
                float g = __builtin_amdgcn_rcpf(1.0f + __expf(-logit));
                float h = hs[grow * DD + ci];
                float cx = ctxLds[ci];
                outF[grow * DD + ci] = g * h + (1.0f - g) * cx;
            }
}

// ---------------- launch ----------------
extern "C" void kernel_launch(void* const* d_in, const int* in_sizes, int n_in,
                              void* d_out, int out_size, void* d_ws, size_t ws_size,
                              hipStream_t stream) {
    const float* hs   = (const float*)d_in[0];
    const float* docs = (const float*)d_in[1];
    const float* Wq   = (const float*)d_in[2];
    const float* bq   = (const float*)d_in[3];
    const float* Wg   = (const float*)d_in[4];
    const float* bgt  = (const float*)d_in[5];
    float* outp = (float*)d_out;
    float* ws = (float*)d_ws;

    float* partial = ws;                               // 32*16*512
    float* qv      = partial + 32 * BB * DD;
    float* ctx     = qv + BB * DD;
    float* ctxb    = ctx + BB * DD;
    float* cand_s  = ctxb + BB * DD;                   // NW3*16*5 = 250240
    int*   cand_i  = (int*)(cand_s + (size_t)NW3 * BB * TOPK);

    k1_mean_partial<<<dim3(32, BB), 128, 0, stream>>>(hs, partial);
    k2_query<<<BB, 512, 0, stream>>>(partial, Wq, bq, qv);
    k3_scores<<<NB3, 512, 0, stream>>>(docs, qv, cand_s, cand_i);
    k4_finalize<<<BB, 256, 0, stream>>>(docs, Wg, bgt, cand_s, cand_i,
                                        ctx, ctxb, outp);
    k5_gemm_fused<<<256, 512, 0, stream>>>(hs, Wg, ctx, ctxb,
                                           outp + 2 * BB * TOPK);
}